// Round 8
// baseline (271.679 us; speedup 1.0000x reference)
//
#include <hip/hip_runtime.h>

#define SCALE 64.0f
#define MARGIN 0.5f

constexpr int BLOCK = 256;
constexpr int GPT = 4;  // float4-groups per thread

typedef float f32x4 __attribute__((ext_vector_type(4)));
typedef int   i32x4 __attribute__((ext_vector_type(4)));

// cos(x) radians via HW TRANS pipe (v_cos_f32 takes revolutions).
__device__ __forceinline__ float cos_fast(float x) {
    float r = x * 0.15915494309189535f;   // radians -> revolutions
    r = r - floorf(r);                    // v_fract_f32
    return __builtin_amdgcn_cosf(r);      // v_cos_f32
}

__device__ __forceinline__ float sample_loss(float d0, float d1, int lab) {
    float pos = lab ? d1 : d0;
    float neg = lab ? d0 : d1;
    float c1 = cos_fast(pos + MARGIN);
    float c0 = cos_fast(neg);
    float d  = (c0 - c1) * SCALE;         // ln - lp
    float t  = __expf(-fabsf(d));         // v_exp_f32
    float s  = __logf(1.0f + t);          // v_log_f32
    return fmaxf(d, 0.0f) + s;            // softplus(d) = logaddexp(lp,ln)-lp
}

__device__ __forceinline__ float quad_loss(f32x4 a, f32x4 b, i32x4 l) {
    float acc;
    acc  = sample_loss(a.x, b.x, l.x);
    acc += sample_loss(a.y, b.y, l.y);
    acc += sample_loss(a.z, b.z, l.z);
    acc += sample_loss(a.w, b.w, l.w);
    return acc;
}

__device__ __forceinline__ float block_reduce(float acc) {
    #pragma unroll
    for (int off = 32; off > 0; off >>= 1)
        acc += __shfl_down(acc, off, 64);
    __shared__ float warp_sums[BLOCK / 64];
    int wave = threadIdx.x >> 6;
    int lane = threadIdx.x & 63;
    if (lane == 0) warp_sums[wave] = acc;
    __syncthreads();
    float s = 0.0f;
    if (threadIdx.x == 0) {
        s = warp_sums[0];
        #pragma unroll
        for (int w = 1; w < BLOCK / 64; ++w) s += warp_sums[w];
    }
    __syncthreads();   // warp_sums reusable afterwards
    return s;
}

__global__ __launch_bounds__(BLOCK) void loss_fused_kernel(
    const float* __restrict__ dist, const int* __restrict__ label,
    float* __restrict__ out, float* __restrict__ partial,
    unsigned* __restrict__ counter, int n, int nblocks)
{
    const int ngroups = n >> 2;  // float4 groups (N=2^24 -> 4M)
    const f32x4* __restrict__ row0 = reinterpret_cast<const f32x4*>(dist);
    const f32x4* __restrict__ row1 = reinterpret_cast<const f32x4*>(dist + n);
    const i32x4* __restrict__ lab4 = reinterpret_cast<const i32x4*>(label);

    const int base = blockIdx.x * (GPT * BLOCK) + threadIdx.x;

    float acc = 0.0f;
    if (base + 3 * BLOCK < ngroups) {
        f32x4 a0 = row0[base];
        f32x4 a1 = row0[base + BLOCK];
        f32x4 a2 = row0[base + 2 * BLOCK];
        f32x4 a3 = row0[base + 3 * BLOCK];
        f32x4 b0 = row1[base];
        f32x4 b1 = row1[base + BLOCK];
        f32x4 b2 = row1[base + 2 * BLOCK];
        f32x4 b3 = row1[base + 3 * BLOCK];
        i32x4 l0 = lab4[base];
        i32x4 l1 = lab4[base + BLOCK];
        i32x4 l2 = lab4[base + 2 * BLOCK];
        i32x4 l3 = lab4[base + 3 * BLOCK];
        acc  = quad_loss(a0, b0, l0);
        acc += quad_loss(a1, b1, l1);
        acc += quad_loss(a2, b2, l2);
        acc += quad_loss(a3, b3, l3);
    } else {
        #pragma unroll
        for (int k = 0; k < GPT; ++k) {
            int g = base + k * BLOCK;
            if (g < ngroups) acc += quad_loss(row0[g], row1[g], lab4[g]);
        }
    }

    float s = block_reduce(acc);

    // --- deterministic last-block final reduction -------------------------
    __shared__ int is_last;
    if (threadIdx.x == 0) {
        // release-store the partial at device (agent) scope, then bump counter
        __hip_atomic_store(&partial[blockIdx.x], s, __ATOMIC_RELEASE,
                           __HIP_MEMORY_SCOPE_AGENT);
        unsigned old = __hip_atomic_fetch_add(counter, 1u, __ATOMIC_ACQ_REL,
                                              __HIP_MEMORY_SCOPE_AGENT);
        is_last = (old == (unsigned)(nblocks - 1));
    }
    __syncthreads();

    if (is_last) {
        // fixed index order -> bitwise-deterministic final sum
        float facc = 0.0f;
        for (int i = threadIdx.x; i < nblocks; i += BLOCK)
            facc += __hip_atomic_load(&partial[i], __ATOMIC_RELAXED,
                                      __HIP_MEMORY_SCOPE_AGENT);
        float total = block_reduce(facc);
        if (threadIdx.x == 0) out[0] = total;
    }
}

extern "C" void kernel_launch(void* const* d_in, const int* in_sizes, int n_in,
                              void* d_out, int out_size, void* d_ws, size_t ws_size,
                              hipStream_t stream) {
    const float* dist  = (const float*)d_in[0];
    const int*   label = (const int*)d_in[1];
    float* out = (float*)d_out;

    unsigned* counter = (unsigned*)d_ws;            // 4 bytes at offset 0
    float* partial = (float*)d_ws + 64;             // 256B-aligned partials

    const int n = in_sizes[0] / 2;          // N samples (dist is 2 x N)
    const int ngroups = n >> 2;             // float4 groups
    const int tile = BLOCK * GPT;
    const int grid = (ngroups + tile - 1) / tile;   // 4096 for N=2^24

    hipMemsetAsync(counter, 0, sizeof(unsigned), stream);  // capture-safe node
    loss_fused_kernel<<<grid, BLOCK, 0, stream>>>(dist, label, out, partial,
                                                  counter, n, grid);
}

// Round 9
// 113.295 us; speedup vs baseline: 2.3980x; 2.3980x over previous
//
#include <hip/hip_runtime.h>

#define SCALE 64.0f
#define MARGIN 0.5f

constexpr int BLOCK = 256;
constexpr int GPT = 4;  // float4-groups per thread

typedef float f32x4 __attribute__((ext_vector_type(4)));
typedef int   i32x4 __attribute__((ext_vector_type(4)));

// cos(x) radians via HW TRANS pipe (v_cos_f32 takes revolutions).
__device__ __forceinline__ float cos_fast(float x) {
    float r = x * 0.15915494309189535f;   // radians -> revolutions
    r = r - floorf(r);                    // v_fract_f32
    return __builtin_amdgcn_cosf(r);      // v_cos_f32
}

__device__ __forceinline__ float sample_loss(float d0, float d1, int lab) {
    float pos = lab ? d1 : d0;
    float neg = lab ? d0 : d1;
    float c1 = cos_fast(pos + MARGIN);
    float c0 = cos_fast(neg);
    float d  = (c0 - c1) * SCALE;         // ln - lp
    float t  = __expf(-fabsf(d));         // v_exp_f32
    float s  = __logf(1.0f + t);          // v_log_f32
    return fmaxf(d, 0.0f) + s;            // softplus(d) = logaddexp(lp,ln)-lp
}

__device__ __forceinline__ float quad_loss(f32x4 a, f32x4 b, i32x4 l) {
    float acc;
    acc  = sample_loss(a.x, b.x, l.x);
    acc += sample_loss(a.y, b.y, l.y);
    acc += sample_loss(a.z, b.z, l.z);
    acc += sample_loss(a.w, b.w, l.w);
    return acc;
}

__device__ __forceinline__ float block_reduce(float acc) {
    #pragma unroll
    for (int off = 32; off > 0; off >>= 1)
        acc += __shfl_down(acc, off, 64);
    __shared__ float warp_sums[BLOCK / 64];
    int wave = threadIdx.x >> 6;
    int lane = threadIdx.x & 63;
    if (lane == 0) warp_sums[wave] = acc;
    __syncthreads();
    float s = 0.0f;
    if (threadIdx.x == 0) {
        s = warp_sums[0];
        #pragma unroll
        for (int w = 1; w < BLOCK / 64; ++w) s += warp_sums[w];
    }
    return s;
}

__global__ __launch_bounds__(BLOCK) void loss_fused_kernel(
    const float* __restrict__ dist, const int* __restrict__ label,
    float* __restrict__ out, unsigned long long* __restrict__ acc_fixed,
    unsigned* __restrict__ counter, int n, int nblocks)
{
    const int ngroups = n >> 2;  // float4 groups (N=2^24 -> 4M)
    const f32x4* __restrict__ row0 = reinterpret_cast<const f32x4*>(dist);
    const f32x4* __restrict__ row1 = reinterpret_cast<const f32x4*>(dist + n);
    const i32x4* __restrict__ lab4 = reinterpret_cast<const i32x4*>(label);

    const int base = blockIdx.x * (GPT * BLOCK) + threadIdx.x;

    float acc = 0.0f;
    if (base + 3 * BLOCK < ngroups) {
        f32x4 a0 = row0[base];
        f32x4 a1 = row0[base + BLOCK];
        f32x4 a2 = row0[base + 2 * BLOCK];
        f32x4 a3 = row0[base + 3 * BLOCK];
        f32x4 b0 = row1[base];
        f32x4 b1 = row1[base + BLOCK];
        f32x4 b2 = row1[base + 2 * BLOCK];
        f32x4 b3 = row1[base + 3 * BLOCK];
        i32x4 l0 = lab4[base];
        i32x4 l1 = lab4[base + BLOCK];
        i32x4 l2 = lab4[base + 2 * BLOCK];
        i32x4 l3 = lab4[base + 3 * BLOCK];
        acc  = quad_loss(a0, b0, l0);
        acc += quad_loss(a1, b1, l1);
        acc += quad_loss(a2, b2, l2);
        acc += quad_loss(a3, b3, l3);
    } else {
        #pragma unroll
        for (int k = 0; k < GPT; ++k) {
            int g = base + k * BLOCK;
            if (g < ngroups) acc += quad_loss(row0[g], row1[g], lab4[g]);
        }
    }

    float s = block_reduce(acc);

    // --- fence-free deterministic epilogue --------------------------------
    // Fixed-point (x 2^32) integer accumulation: associative -> bitwise
    // deterministic regardless of arrival order. Plain relaxed atomics only
    // (memory-side RMW at the coherence point) -- NO release/acquire fences
    // (R8: per-block agent-scope fences cost ~400 us in L2 writebacks).
    if (threadIdx.x == 0) {
        long long f = llrint((double)s * 4294967296.0);  // one f64 op/block
        unsigned long long oldv = atomicAdd(acc_fixed, (unsigned long long)f);
        // Force the RMW to have completed (use of return value) before the
        // counter bump, so counter==nblocks implies all acc-adds are visible.
        asm volatile("" :: "v"(oldv));
        unsigned oldc = atomicAdd(counter, 1u);
        if (oldc == (unsigned)(nblocks - 1)) {
            unsigned long long tot = atomicAdd(acc_fixed, 0ull); // atomic read
            out[0] = (float)((double)(long long)tot * (1.0 / 4294967296.0));
        }
    }
}

extern "C" void kernel_launch(void* const* d_in, const int* in_sizes, int n_in,
                              void* d_out, int out_size, void* d_ws, size_t ws_size,
                              hipStream_t stream) {
    const float* dist  = (const float*)d_in[0];
    const int*   label = (const int*)d_in[1];
    float* out = (float*)d_out;

    unsigned* counter = (unsigned*)d_ws;                              // +0
    unsigned long long* acc_fixed =
        (unsigned long long*)((char*)d_ws + 8);                       // +8

    const int n = in_sizes[0] / 2;          // N samples (dist is 2 x N)
    const int ngroups = n >> 2;             // float4 groups
    const int tile = BLOCK * GPT;
    const int grid = (ngroups + tile - 1) / tile;   // 4096 for N=2^24

    hipMemsetAsync(d_ws, 0, 16, stream);    // zero counter + accumulator
    loss_fused_kernel<<<grid, BLOCK, 0, stream>>>(dist, label, out, acc_fixed,
                                                  counter, n, grid);
}

// Round 10
// 44.195 us; speedup vs baseline: 6.1473x; 2.5635x over previous
//
#include <hip/hip_runtime.h>

#define SCALE 64.0f
#define MARGIN 0.5f

constexpr int BLOCK = 256;
constexpr int GPT = 4;      // float4-groups per thread
constexpr int NLINES = 8;   // contention-spreading fan-out
constexpr float FIXSCALE = 16777216.0f;        // 2^24
constexpr double INV_FIXSCALE = 1.0 / 16777216.0;

typedef float f32x4 __attribute__((ext_vector_type(4)));
typedef int   i32x4 __attribute__((ext_vector_type(4)));

// cos(x) radians via HW TRANS pipe (v_cos_f32 takes revolutions).
__device__ __forceinline__ float cos_fast(float x) {
    float r = x * 0.15915494309189535f;   // radians -> revolutions
    r = r - floorf(r);                    // v_fract_f32
    return __builtin_amdgcn_cosf(r);      // v_cos_f32
}

__device__ __forceinline__ float sample_loss(float d0, float d1, int lab) {
    float pos = lab ? d1 : d0;
    float neg = lab ? d0 : d1;
    float c1 = cos_fast(pos + MARGIN);
    float c0 = cos_fast(neg);
    float d  = (c0 - c1) * SCALE;         // ln - lp
    float t  = __expf(-fabsf(d));         // v_exp_f32
    float s  = __logf(1.0f + t);          // v_log_f32
    return fmaxf(d, 0.0f) + s;            // softplus(d) = logaddexp(lp,ln)-lp
}

__device__ __forceinline__ float quad_loss(f32x4 a, f32x4 b, i32x4 l) {
    float acc;
    acc  = sample_loss(a.x, b.x, l.x);
    acc += sample_loss(a.y, b.y, l.y);
    acc += sample_loss(a.z, b.z, l.z);
    acc += sample_loss(a.w, b.w, l.w);
    return acc;
}

__device__ __forceinline__ float block_reduce(float acc) {
    #pragma unroll
    for (int off = 32; off > 0; off >>= 1)
        acc += __shfl_down(acc, off, 64);
    __shared__ float warp_sums[BLOCK / 64];
    int wave = threadIdx.x >> 6;
    int lane = threadIdx.x & 63;
    if (lane == 0) warp_sums[wave] = acc;
    __syncthreads();
    float s = 0.0f;
    if (threadIdx.x == 0) {
        s = warp_sums[0];
        #pragma unroll
        for (int w = 1; w < BLOCK / 64; ++w) s += warp_sums[w];
    }
    return s;
}

__global__ __launch_bounds__(BLOCK) void loss_fused_kernel(
    const float* __restrict__ dist, const int* __restrict__ label,
    float* __restrict__ out, char* __restrict__ ws, int n, int nblocks)
{
    const int ngroups = n >> 2;  // float4 groups (N=2^24 -> 4M)
    const f32x4* __restrict__ row0 = reinterpret_cast<const f32x4*>(dist);
    const f32x4* __restrict__ row1 = reinterpret_cast<const f32x4*>(dist + n);
    const i32x4* __restrict__ lab4 = reinterpret_cast<const i32x4*>(label);

    const int base = blockIdx.x * (GPT * BLOCK) + threadIdx.x;

    float acc = 0.0f;
    if (base + 3 * BLOCK < ngroups) {
        f32x4 a0 = row0[base];
        f32x4 a1 = row0[base + BLOCK];
        f32x4 a2 = row0[base + 2 * BLOCK];
        f32x4 a3 = row0[base + 3 * BLOCK];
        f32x4 b0 = row1[base];
        f32x4 b1 = row1[base + BLOCK];
        f32x4 b2 = row1[base + 2 * BLOCK];
        f32x4 b3 = row1[base + 3 * BLOCK];
        i32x4 l0 = lab4[base];
        i32x4 l1 = lab4[base + BLOCK];
        i32x4 l2 = lab4[base + 2 * BLOCK];
        i32x4 l3 = lab4[base + 3 * BLOCK];
        acc  = quad_loss(a0, b0, l0);
        acc += quad_loss(a1, b1, l1);
        acc += quad_loss(a2, b2, l2);
        acc += quad_loss(a3, b3, l3);
    } else {
        #pragma unroll
        for (int k = 0; k < GPT; ++k) {
            int g = base + k * BLOCK;
            if (g < ngroups) acc += quad_loss(row0[g], row1[g], lab4[g]);
        }
    }

    float s = block_reduce(acc);

    // --- hierarchical fence-free deterministic epilogue -------------------
    // 8 acc lines + 8 counter lines (256B apart): ~512 relaxed RMWs per line
    // arriving over ~30us >> 9ns/RMW service (R9 lesson) -> fully hidden.
    // Fixed-point x 2^24 integer accumulation = associative = deterministic.
    // All reads of shared lines use RMW (atomicAdd 0); plain loads can see a
    // stale L2 copy (memory-side atomics don't invalidate XCD L2s).
    if (threadIdx.x == 0) {
        const int k = blockIdx.x & (NLINES - 1);
        unsigned long long* acc_p = (unsigned long long*)(ws + k * 256);
        unsigned* cnt_p = (unsigned*)(ws + 2048 + k * 256);
        unsigned* lines_done = (unsigned*)(ws + 4096);

        long long f = llrintf(s * FIXSCALE);
        unsigned long long olda = atomicAdd(acc_p, (unsigned long long)f);
        asm volatile("" :: "v"(olda));   // acc-add completed before cnt bump

        const unsigned quota =
            (unsigned)(nblocks >> 3) + (((nblocks & 7) > k) ? 1u : 0u);
        unsigned oldc = atomicAdd(cnt_p, 1u);
        if (oldc == quota - 1u) {
            asm volatile("" :: "v"(oldc));
            unsigned oldd = atomicAdd(lines_done, 1u);
            if (oldd == (unsigned)NLINES - 1u) {
                long long tot = 0;
                #pragma unroll
                for (int j = 0; j < NLINES; ++j) {   // fixed order: determinism
                    unsigned long long* ap = (unsigned long long*)(ws + j * 256);
                    tot += (long long)atomicAdd(ap, 0ull);   // RMW-read
                }
                out[0] = (float)((double)tot * INV_FIXSCALE);
            }
        }
    }
}

extern "C" void kernel_launch(void* const* d_in, const int* in_sizes, int n_in,
                              void* d_out, int out_size, void* d_ws, size_t ws_size,
                              hipStream_t stream) {
    const float* dist  = (const float*)d_in[0];
    const int*   label = (const int*)d_in[1];
    float* out = (float*)d_out;

    const int n = in_sizes[0] / 2;          // N samples (dist is 2 x N)
    const int ngroups = n >> 2;             // float4 groups
    const int tile = BLOCK * GPT;
    const int grid = (ngroups + tile - 1) / tile;   // 4096 for N=2^24

    hipMemsetAsync(d_ws, 0, 4352, stream);  // zero acc/cnt lines + lines_done
    loss_fused_kernel<<<grid, BLOCK, 0, stream>>>(dist, label, out,
                                                  (char*)d_ws, n, grid);
}

// Round 11
// 37.724 us; speedup vs baseline: 7.2018x; 1.1715x over previous
//
#include <hip/hip_runtime.h>

#define SCALE 64.0f
#define MARGIN 0.5f

constexpr int BLOCK = 256;
constexpr int GPT = 8;  // float4-groups per thread; 2048 blocks exactly tile N=2^24

typedef float f32x4 __attribute__((ext_vector_type(4)));
typedef int   i32x4 __attribute__((ext_vector_type(4)));

// cos(x) radians via HW TRANS pipe (v_cos_f32 takes revolutions).
__device__ __forceinline__ float cos_fast(float x) {
    float r = x * 0.15915494309189535f;   // radians -> revolutions
    r = r - floorf(r);                    // v_fract_f32
    return __builtin_amdgcn_cosf(r);      // v_cos_f32
}

__device__ __forceinline__ float sample_loss(float d0, float d1, int lab) {
    float pos = lab ? d1 : d0;
    float neg = lab ? d0 : d1;
    float c1 = cos_fast(pos + MARGIN);
    float c0 = cos_fast(neg);
    float d  = (c0 - c1) * SCALE;         // ln - lp
    float t  = __expf(-fabsf(d));         // v_exp_f32
    float s  = __logf(1.0f + t);          // v_log_f32
    return fmaxf(d, 0.0f) + s;            // softplus(d) = logaddexp(lp,ln)-lp
}

__device__ __forceinline__ float quad_loss(f32x4 a, f32x4 b, i32x4 l) {
    float acc;
    acc  = sample_loss(a.x, b.x, l.x);
    acc += sample_loss(a.y, b.y, l.y);
    acc += sample_loss(a.z, b.z, l.z);
    acc += sample_loss(a.w, b.w, l.w);
    return acc;
}

template <int BS>
__device__ __forceinline__ float block_reduce(float acc) {
    #pragma unroll
    for (int off = 32; off > 0; off >>= 1)
        acc += __shfl_down(acc, off, 64);
    __shared__ float warp_sums[BS / 64];
    int wave = threadIdx.x >> 6;
    int lane = threadIdx.x & 63;
    if (lane == 0) warp_sums[wave] = acc;
    __syncthreads();
    float s = 0.0f;
    if (threadIdx.x == 0) {
        s = warp_sums[0];
        #pragma unroll
        for (int w = 1; w < BS / 64; ++w) s += warp_sums[w];
    }
    return s;
}

__global__ __launch_bounds__(BLOCK) void loss_partial_kernel(
    const float* __restrict__ dist, const int* __restrict__ label,
    float* __restrict__ partial, int n)
{
    const int ngroups = n >> 2;  // float4 groups (N=2^24 -> 4M)
    const f32x4* __restrict__ row0 = reinterpret_cast<const f32x4*>(dist);
    const f32x4* __restrict__ row1 = reinterpret_cast<const f32x4*>(dist + n);
    const i32x4* __restrict__ lab4 = reinterpret_cast<const i32x4*>(label);

    const int base = blockIdx.x * (GPT * BLOCK) + threadIdx.x;

    float acc = 0.0f;
    if (base + (GPT - 1) * BLOCK < ngroups) {
        // exact-tiling fast path (always taken for N=2^24): branch-free,
        // 8 independent group-triples for the scheduler to pipeline
        #pragma unroll
        for (int k = 0; k < GPT; ++k) {
            int g = base + k * BLOCK;
            acc += quad_loss(row0[g], row1[g], lab4[g]);
        }
    } else {
        #pragma unroll
        for (int k = 0; k < GPT; ++k) {
            int g = base + k * BLOCK;
            if (g < ngroups) acc += quad_loss(row0[g], row1[g], lab4[g]);
        }
    }

    float s = block_reduce<BLOCK>(acc);
    if (threadIdx.x == 0) partial[blockIdx.x] = s;
}

__global__ __launch_bounds__(BLOCK) void reduce_partials_kernel(
    const float* __restrict__ partial, float* __restrict__ out, int nparts)
{
    float acc = 0.0f;
    for (int i = threadIdx.x; i < nparts; i += BLOCK) acc += partial[i];
    float s = block_reduce<BLOCK>(acc);
    if (threadIdx.x == 0) out[0] = s;
}

extern "C" void kernel_launch(void* const* d_in, const int* in_sizes, int n_in,
                              void* d_out, int out_size, void* d_ws, size_t ws_size,
                              hipStream_t stream) {
    const float* dist  = (const float*)d_in[0];
    const int*   label = (const int*)d_in[1];
    float* out = (float*)d_out;
    float* partial = (float*)d_ws;

    const int n = in_sizes[0] / 2;          // N samples (dist is 2 x N)
    const int ngroups = n >> 2;             // float4 groups
    const int tile = BLOCK * GPT;
    const int grid = (ngroups + tile - 1) / tile;   // 2048 for N=2^24

    loss_partial_kernel<<<grid, BLOCK, 0, stream>>>(dist, label, partial, n);
    reduce_partials_kernel<<<1, BLOCK, 0, stream>>>(partial, out, grid);
}